// Round 4
// baseline (266.068 us; speedup 1.0000x reference)
//
#include <hip/hip_runtime.h>
#include <math.h>

#define T_STEPS 256
#define BATCH   128
#define DIMD    512
#define NROWS   (T_STEPS * BATCH)   // 32768
#define CH      16                  // scan chunk (publish granularity)

#define INV2PI  0.15915494309189535f
#define L2E     1.4426950408889634f
#define TWO_L2E 2.8853900817779268f

#if __has_builtin(__builtin_amdgcn_sinf)
#define HW_SIN(x) __builtin_amdgcn_sinf(x)   // sin(2*pi*x), x in revolutions
#else
__device__ __forceinline__ float HW_SIN(float x) { return __sinf(x * 6.283185307179586f); }
#endif
#if __has_builtin(__builtin_amdgcn_exp2f)
#define EXP2(x) __builtin_amdgcn_exp2f(x)
#else
#define EXP2(x) exp2f(x)
#endif
#if __has_builtin(__builtin_amdgcn_rcpf)
#define RCP(x) __builtin_amdgcn_rcpf(x)
#else
#define RCP(x) (1.0f / (x))
#endif

// ---------------------------------------------------------------------------
// qconsts: 4 gates in parallel (4 waves x 64 lanes, 4 amplitudes/lane).
// E(theta) = A + R*sin(theta + phi). Outputs per gate (scaled for scan):
// gc[4g+0]=scale*A, gc[4g+1]=scale*R, gc[4g+2]=phi_rev, gc[4g+3]=sumWh/2pi
// scale = -L2E (sigmoid gates f,i,o) or +2*L2E (tanh gate g).
// ---------------------------------------------------------------------------
__global__ __launch_bounds__(256) void qconsts(
    const float* __restrict__ P0, const float* __restrict__ P1,
    const float* __restrict__ P2, const float* __restrict__ P3,
    const float* __restrict__ W0, const float* __restrict__ W1,
    const float* __restrict__ W2, const float* __restrict__ W3,
    float* __restrict__ gc)
{
    const int g    = threadIdx.x >> 6;
    const int lane = threadIdx.x & 63;
    const float* P = (g == 0) ? P0 : (g == 1) ? P1 : (g == 2) ? P2 : P3;
    const float* W = (g == 0) ? W0 : (g == 1) ? W1 : (g == 2) ? W2 : W3;

    __shared__ float s0r[4][256], s0i[4][256], s1r[4][256], s1i[4][256];

#pragma unroll
    for (int j = 0; j < 4; ++j) {
        const int k = lane + 64 * j;
        s0r[g][k] = (k == 0)   ? 1.0f : 0.0f;  s0i[g][k] = 0.0f;
        s1r[g][k] = (k == 128) ? 1.0f : 0.0f;  s1i[g][k] = 0.0f;
    }
    __syncthreads();

    for (int l = 0; l < 2; ++l) {
        for (int w = 0; w < 8; ++w) {
            const float phi = P[l * 24 + w * 3 + 0];
            const float th  = P[l * 24 + w * 3 + 1];
            const float om  = P[l * 24 + w * 3 + 2];
            float sh, chh; __sincosf(0.5f * th, &sh, &chh);
            float sp, cp;  __sincosf(0.5f * (phi + om), &sp, &cp);
            float sm, cm;  __sincosf(0.5f * (phi - om), &sm, &cm);
            const float m00r =  cp * chh, m00i = -sp * chh;
            const float m01r = -cm * sh,  m01i = -sm * sh;
            const float m10r =  cm * sh,  m10i = -sm * sh;
            const float m11r =  cp * chh, m11i =  sp * chh;

            const int shift = 7 - w;
            const int mask  = 1 << shift;

            float n0r[4], n0i[4], n1r[4], n1i[4];
#pragma unroll
            for (int j = 0; j < 4; ++j) {
                const int k  = lane + 64 * j;
                const int bit = (k >> shift) & 1;
                const int i0 = k & ~mask, i1 = k | mask;
                const float a0r = s0r[g][i0], a0i = s0i[g][i0];
                const float a1r = s0r[g][i1], a1i = s0i[g][i1];
                const float b0r = s1r[g][i0], b0i = s1i[g][i0];
                const float b1r = s1r[g][i1], b1i = s1i[g][i1];
                const float mr0 = bit ? m10r : m00r, mi0 = bit ? m10i : m00i;
                const float mr1 = bit ? m11r : m01r, mi1 = bit ? m11i : m01i;
                n0r[j] = mr0 * a0r - mi0 * a0i + mr1 * a1r - mi1 * a1i;
                n0i[j] = mr0 * a0i + mi0 * a0r + mr1 * a1i + mi1 * a1r;
                n1r[j] = mr0 * b0r - mi0 * b0i + mr1 * b1r - mi1 * b1i;
                n1i[j] = mr0 * b0i + mi0 * b0r + mr1 * b1i + mi1 * b1r;
            }
            __syncthreads();
#pragma unroll
            for (int j = 0; j < 4; ++j) {
                const int k = lane + 64 * j;
                s0r[g][k] = n0r[j]; s0i[g][k] = n0i[j];
                s1r[g][k] = n1r[j]; s1i[g][k] = n1i[j];
            }
            __syncthreads();
        }
        // CNOT chain permutation
        float n0r[4], n0i[4], n1r[4], n1i[4];
#pragma unroll
        for (int j = 0; j < 4; ++j) {
            int src = lane + 64 * j;
            for (int w = 6; w >= 0; --w) {
                const int cb = (src >> (7 - w)) & 1;
                src ^= cb << (6 - w);
            }
            n0r[j] = s0r[g][src]; n0i[j] = s0i[g][src];
            n1r[j] = s1r[g][src]; n1i[j] = s1i[g][src];
        }
        __syncthreads();
#pragma unroll
        for (int j = 0; j < 4; ++j) {
            const int k = lane + 64 * j;
            s0r[g][k] = n0r[j]; s0i[g][k] = n0i[j];
            s1r[g][k] = n1r[j]; s1i[g][k] = n1i[j];
        }
        __syncthreads();
    }

    float t00 = 0, t11 = 0, t01 = 0;
#pragma unroll
    for (int j = 0; j < 4; ++j) {
        const int k = lane + 64 * j;
        const float z = (k < 128) ? 1.0f : -1.0f;
        t00 += z * (s0r[g][k] * s0r[g][k] + s0i[g][k] * s0i[g][k]);
        t11 += z * (s1r[g][k] * s1r[g][k] + s1i[g][k] * s1i[g][k]);
        t01 += z * (s0i[g][k] * s1r[g][k] - s0r[g][k] * s1i[g][k]);
    }
    float tsw = 0;
#pragma unroll
    for (int j = 0; j < 8; ++j) tsw += W[512 + lane + 64 * j];

    for (int off = 32; off; off >>= 1) {
        t00 += __shfl_xor(t00, off);
        t11 += __shfl_xor(t11, off);
        t01 += __shfl_xor(t01, off);
        tsw += __shfl_xor(tsw, off);
    }
    if (lane == 0) {
        const float A  = 0.5f * (t00 + t11);
        const float Bc = 0.5f * (t00 - t11);
        const float Bs = -t01;
        const float R  = sqrtf(Bc * Bc + Bs * Bs);
        const float ph = atan2f(Bc, Bs) * INV2PI;
        const float sc = (g == 2) ? TWO_L2E : -L2E;
        gc[4 * g + 0] = sc * A;
        gc[4 * g + 1] = sc * R;
        gc[4 * g + 2] = ph;
        gc[4 * g + 3] = tsw * INV2PI;
    }
}

// ---------------------------------------------------------------------------
// X4[t*B+b] = (f,i,g,o) sin-args in revolutions: (dot+b0)/2pi + phi_rev.
// ---------------------------------------------------------------------------
__global__ __launch_bounds__(256) void gemv4(
    const float* __restrict__ x,
    const float* __restrict__ Wf, const float* __restrict__ Wi,
    const float* __restrict__ Wg, const float* __restrict__ Wo,
    const float* __restrict__ bfp, const float* __restrict__ bip,
    const float* __restrict__ bgp, const float* __restrict__ bop,
    const float* __restrict__ gc,
    float4* __restrict__ X4)
{
    const int lane = threadIdx.x & 63;
    const int wid  = threadIdx.x >> 6;
    const int row  = (blockIdx.x << 2) + wid;

    const float4* xr = (const float4*)(x + (size_t)row * DIMD);
    const float4 xa = xr[lane];
    const float4 xb = xr[lane + 64];

    const float4* wf = (const float4*)Wf;
    const float4* wi = (const float4*)Wi;
    const float4* wg = (const float4*)Wg;
    const float4* wo = (const float4*)Wo;
    const float4 fa = wf[lane], fb = wf[lane + 64];
    const float4 ia = wi[lane], ib = wi[lane + 64];
    const float4 ga = wg[lane], gb = wg[lane + 64];
    const float4 oa = wo[lane], ob = wo[lane + 64];

    float sf = xa.x * fa.x + xa.y * fa.y + xa.z * fa.z + xa.w * fa.w
             + xb.x * fb.x + xb.y * fb.y + xb.z * fb.z + xb.w * fb.w;
    float si = xa.x * ia.x + xa.y * ia.y + xa.z * ia.z + xa.w * ia.w
             + xb.x * ib.x + xb.y * ib.y + xb.z * ib.z + xb.w * ib.w;
    float sg = xa.x * ga.x + xa.y * ga.y + xa.z * ga.z + xa.w * ga.w
             + xb.x * gb.x + xb.y * gb.y + xb.z * gb.z + xb.w * gb.w;
    float so = xa.x * oa.x + xa.y * oa.y + xa.z * oa.z + xa.w * oa.w
             + xb.x * ob.x + xb.y * ob.y + xb.z * ob.z + xb.w * ob.w;

    for (int off = 32; off; off >>= 1) {
        sf += __shfl_xor(sf, off);
        si += __shfl_xor(si, off);
        sg += __shfl_xor(sg, off);
        so += __shfl_xor(so, off);
    }
    if (lane == 0) {
        X4[row] = make_float4(fmaf(sf + bfp[0], INV2PI, gc[2]),
                              fmaf(si + bip[0], INV2PI, gc[6]),
                              fmaf(sg + bgp[0], INV2PI, gc[10]),
                              fmaf(so + bop[0], INV2PI, gc[14]));
    }
}

// ---------------------------------------------------------------------------
// Fused scan + broadcast. Grid 259 x 256.
// Block 0 waves 0,1: LSTM recurrence (64 chains each), publish hProg[wv]
// every CH steps with agent-scope release. All other waves: one quarter-t
// write task each (poll-acquire, then stream 64 KB).
// ---------------------------------------------------------------------------
__global__ __launch_bounds__(256) void scan_write(
    const float4* __restrict__ X4, const float* __restrict__ gc,
    float* __restrict__ Hs, float* __restrict__ cfin,
    float4* __restrict__ out4, int* __restrict__ hProg)
{
    const int wv   = threadIdx.x >> 6;
    const int lane = threadIdx.x & 63;
    const int gw   = blockIdx.x * 4 + wv;

    if (gw < 2) {
        // ---------------- scan ----------------
        const int b = threadIdx.x;   // 0..127
        const float Af = gc[0],  Rf = gc[1],  swf = gc[3];
        const float Ai = gc[4],  Ri = gc[5],  swi = gc[7];
        const float Ag = gc[8],  Rg = gc[9],  swg = gc[11];
        const float Ao = gc[12], Ro = gc[13], swo = gc[15];

        float4 p[CH], q[CH];
#pragma unroll
        for (int j = 0; j < CH; ++j) p[j] = X4[j * BATCH + b];

        float c = 0.0f, h = 0.0f;
        for (int k = 0; k < T_STEPS / CH; ++k) {
            const int tb = k * CH;
            // prefetch next chunk (pad covers the final one)
#pragma unroll
            for (int j = 0; j < CH; ++j) q[j] = X4[(tb + CH + j) * BATCH + b];
#pragma unroll
            for (int j = 0; j < CH; ++j) {
                const float4 xv = p[j];
                const float thf = fmaf(h, swf, xv.x);
                const float thi = fmaf(h, swi, xv.y);
                const float thg = fmaf(h, swg, xv.z);
                const float tho = fmaf(h, swo, xv.w);
                const float Ef = fmaf(Rf, HW_SIN(thf), Af);  // = -L2E*E
                const float Ei = fmaf(Ri, HW_SIN(thi), Ai);
                const float Eg = fmaf(Rg, HW_SIN(thg), Ag);  // = 2*L2E*E
                const float Eo = fmaf(Ro, HW_SIN(tho), Ao);
                const float fg = RCP(1.0f + EXP2(Ef));
                const float ig = RCP(1.0f + EXP2(Ei));
                const float og = RCP(1.0f + EXP2(Eo));
                const float gg = 1.0f - 2.0f * RCP(EXP2(Eg) + 1.0f);
                c = fmaf(fg, c, ig * gg);
                h = og * (1.0f - 2.0f * RCP(EXP2(c * TWO_L2E) + 1.0f));
                Hs[(tb + j) * BATCH + b] = h;
            }
            if (k == T_STEPS / CH - 1) cfin[b] = c;
            if (lane == 0)
                __hip_atomic_store(&hProg[wv], tb + CH, __ATOMIC_RELEASE,
                                   __HIP_MEMORY_SCOPE_AGENT);
#pragma unroll
            for (int j = 0; j < CH; ++j) p[j] = q[j];
        }
        return;
    }

    // ---------------- writers ----------------
    const int task = gw - 2;
    if (task >= 258 * 4) return;
    const int t = task >> 2;          // 0..257 (256=hx, 257=cx)
    const int qd = task & 3;          // quarter: b in [qd*32, qd*32+32)
    const int pidx = (qd < 2) ? 0 : 1;
    const int need = (t < 256) ? (t + 1) : 256;

    while (__hip_atomic_load(&hProg[pidx], __ATOMIC_ACQUIRE,
                             __HIP_MEMORY_SCOPE_AGENT) < need)
        __builtin_amdgcn_s_sleep(8);

    const float* src = (t == 257) ? cfin : (Hs + ((t >= 256 ? 255 : t) * BATCH));
    const float hv = src[qd * 32 + (lane & 31)];

    size_t base = (t < 256) ? ((size_t)t * 16384)
                : (t == 256 ? (size_t)4194304 : (size_t)4210688);
    base += (size_t)qd * 4096;
#pragma unroll 8
    for (int j = 0; j < 64; ++j) {
        const float v = __shfl(hv, j >> 1);
        out4[base + j * 64 + lane] = make_float4(v, v, v, v);
    }
}

extern "C" void kernel_launch(void* const* d_in, const int* in_sizes, int n_in,
                              void* d_out, int out_size, void* d_ws, size_t ws_size,
                              hipStream_t stream)
{
    const float* inp = (const float*)d_in[0];
    const float* Wf  = (const float*)d_in[1];
    const float* bfv = (const float*)d_in[2];
    const float* Pf  = (const float*)d_in[3];
    const float* Wi  = (const float*)d_in[4];
    const float* biv = (const float*)d_in[5];
    const float* Pi  = (const float*)d_in[6];
    const float* Wg  = (const float*)d_in[7];
    const float* bgv = (const float*)d_in[8];
    const float* Pg  = (const float*)d_in[9];
    const float* Wo  = (const float*)d_in[10];
    const float* bov = (const float*)d_in[11];
    const float* Po  = (const float*)d_in[12];

    float4* X4  = (float4*)d_ws;                    // NROWS + CH*BATCH entries
    float*  Hs  = (float*)(X4 + NROWS + CH * BATCH);
    float*  cfin = Hs + NROWS;                      // 128
    float*  gc  = cfin + BATCH;                     // 16
    int*    hProg = (int*)(gc + 16);                // 2

    hipMemsetAsync(hProg, 0, 2 * sizeof(int), stream);
    qconsts<<<1, 256, 0, stream>>>(Pf, Pi, Pg, Po, Wf, Wi, Wg, Wo, gc);
    gemv4<<<NROWS / 4, 256, 0, stream>>>(inp, Wf, Wi, Wg, Wo,
                                         bfv, biv, bgv, bov, gc, X4);
    scan_write<<<259, 256, 0, stream>>>(X4, gc, Hs, cfin,
                                        (float4*)d_out, hProg);
}